// Round 8
// baseline (327.086 us; speedup 1.0000x reference)
//
#include <hip/hip_runtime.h>

#define N_NODES 100000
#define DIM 256
#define KC 16
#define NE 3200000
#define CHUNK 32                 // nodes per block-iteration in fused kernel
#define NCHUNKS (N_NODES / CHUNK)   // 3125 exact

__device__ __forceinline__ float bflo(unsigned u) { return __uint_as_float(u << 16); }
__device__ __forceinline__ float bfhi(unsigned u) { return __uint_as_float(u & 0xffff0000u); }
__device__ __forceinline__ unsigned short f2bf(float f) {  // RNE
    unsigned u = __float_as_uint(f);
    return (unsigned short)((u + 0x7fffu + ((u >> 16) & 1u)) >> 16);
}
__device__ __forceinline__ unsigned packbf(float a, float b) {
    return (unsigned)f2bf(a) | ((unsigned)f2bf(b) << 16);
}

// ---------------------------------------------------------------------------
// Fused assignment + S^T X. Per chunk of 32 nodes:
//  phase A: stage X chunk in LDS (rows stride 65 float4), 8 threads/node
//           compute logits from LDS X + LDS W, butterfly-reduce, softmax,
//           write S (f32, d_out), Sb (bf16, ws), ps (LDS).
//  phase B: thread t owns column d=t; stx[k][d] += sum_i ps[i][k]*Xs[i][d].
// X crosses HBM exactly once for both uses. cs accumulated in regs.
// ---------------------------------------------------------------------------
template <bool WRITE_BF16>
__global__ __launch_bounds__(256) void k_assign_stx(const float4* __restrict__ X4,
                                                    const float4* __restrict__ W4,
                                                    const float* __restrict__ bias,
                                                    float* __restrict__ S,
                                                    unsigned* __restrict__ Sb,
                                                    float* __restrict__ cs_g,
                                                    float* __restrict__ stx) {
    __shared__ float4 Xs4[CHUNK * 65];   // 32 rows x 64 f4, stride 65 (16B-aligned, uniform banks)
    __shared__ float4 Wl[KC * 65];       // 16 rows x 64 f4, stride 65
    __shared__ float4 ps4[CHUNK * 4];    // p[node][16] as 4 float4
    __shared__ float csred[4][KC];

    for (int t = threadIdx.x; t < KC * 64; t += 256) {
        int k = t >> 6, c4 = t & 63;
        Wl[k * 65 + c4] = W4[t];
    }

    const int il = threadIdx.x >> 3;   // node within chunk (0..31)
    const int q8 = threadIdx.x & 7;    // eighth of the row (0..7)
    const int wv = threadIdx.x >> 6;
    const int d  = threadIdx.x;        // phase-B column

    float st[KC], csacc[KC];
    #pragma unroll
    for (int k = 0; k < KC; k++) { st[k] = 0.f; csacc[k] = 0.f; }

    for (int ch = blockIdx.x; ch < NCHUNKS; ch += gridDim.x) {
        const int base = ch * CHUNK;
        __syncthreads();   // protect Xs/ps reuse from previous iteration
        // ---- stage X: each wave loads full rows (64 f4 = 1 KB, coalesced)
        {
            const int lane = threadIdx.x & 63;
            for (int r = wv; r < CHUNK; r += 4)
                Xs4[r * 65 + lane] = X4[(size_t)(base + r) * 64 + lane];
        }
        __syncthreads();

        // ---- phase A: logits from LDS
        float acc[KC];
        #pragma unroll
        for (int k = 0; k < KC; k++) acc[k] = 0.f;
        #pragma unroll
        for (int j = 0; j < 8; j++) {
            float4 x = Xs4[il * 65 + q8 + 8 * j];
            #pragma unroll
            for (int k = 0; k < KC; k++) {
                float4 w = Wl[k * 65 + q8 + 8 * j];
                acc[k] += x.x * w.x + x.y * w.y + x.z * w.z + x.w * w.w;
            }
        }
        #pragma unroll
        for (int k = 0; k < KC; k++) {
            acc[k] += __shfl_xor(acc[k], 1);
            acc[k] += __shfl_xor(acc[k], 2);
            acc[k] += __shfl_xor(acc[k], 4);
            acc[k] += bias[k];
        }
        float m = acc[0];
        #pragma unroll
        for (int k = 1; k < KC; k++) m = fmaxf(m, acc[k]);
        float p[KC], ssum = 0.f;
        #pragma unroll
        for (int k = 0; k < KC; k++) { float e = __expf(acc[k] - m); p[k] = e; ssum += e; }
        float inv = 1.f / ssum;
        #pragma unroll
        for (int k = 0; k < KC; k++) p[k] *= inv;

        const int node = base + il;
        if (q8 < 4)
            ((float4*)(S + (size_t)node * KC))[q8] =
                make_float4(p[4 * q8], p[4 * q8 + 1], p[4 * q8 + 2], p[4 * q8 + 3]);
        if (WRITE_BF16 && (q8 == 4 || q8 == 5)) {
            int h = q8 - 4;
            ((uint4*)(Sb + (size_t)node * 8))[h] =
                make_uint4(packbf(p[8 * h + 0], p[8 * h + 1]),
                           packbf(p[8 * h + 2], p[8 * h + 3]),
                           packbf(p[8 * h + 4], p[8 * h + 5]),
                           packbf(p[8 * h + 6], p[8 * h + 7]));
        }
        if (q8 >= 4) {
            int h = q8 - 4;   // also covers ps writes for h=0..3
            ps4[il * 4 + h] = make_float4(p[4 * h], p[4 * h + 1], p[4 * h + 2], p[4 * h + 3]);
        }
        if (q8 == 0) {
            #pragma unroll
            for (int k = 0; k < KC; k++) csacc[k] += p[k];
        }
        __syncthreads();

        // ---- phase B: stx accumulation, thread owns column d
        const float* Xsf = (const float*)Xs4;
        #pragma unroll 4
        for (int i = 0; i < CHUNK; i++) {
            float x = Xsf[i * 260 + d];
            float4 p0 = ps4[i * 4 + 0], p1 = ps4[i * 4 + 1];
            float4 p2 = ps4[i * 4 + 2], p3 = ps4[i * 4 + 3];
            st[0]  += p0.x * x; st[1]  += p0.y * x; st[2]  += p0.z * x; st[3]  += p0.w * x;
            st[4]  += p1.x * x; st[5]  += p1.y * x; st[6]  += p1.z * x; st[7]  += p1.w * x;
            st[8]  += p2.x * x; st[9]  += p2.y * x; st[10] += p2.z * x; st[11] += p2.w * x;
            st[12] += p3.x * x; st[13] += p3.y * x; st[14] += p3.z * x; st[15] += p3.w * x;
        }
    }

    // ---- epilogues: stx atomics (one per k per thread) and cs reduction
    #pragma unroll
    for (int k = 0; k < KC; k++) atomicAdd(&stx[k * DIM + d], st[k]);

    #pragma unroll
    for (int k = 0; k < KC; k++) {
        float v = csacc[k];
        #pragma unroll
        for (int off = 32; off >= 1; off >>= 1) v += __shfl_xor(v, off);
        if ((threadIdx.x & 63) == 0) csred[wv][k] = v;
    }
    __syncthreads();
    if (threadIdx.x < KC) {
        int t = threadIdx.x;
        atomicAdd(&cs_g[t], csred[0][t] + csred[1][t] + csred[2][t] + csred[3][t]);
    }
}

// ---------------------------------------------------------------------------
// Per-edge fused: m2 += adj; tr += adj*dot(S[row],S[col]); left += adj*S[row].
// BF16 path gathers 32 B rows from L2-resident Sb; block-level reduction.
// ---------------------------------------------------------------------------
template <bool BF16>
__global__ __launch_bounds__(256) void k_edges(const int* __restrict__ rows,
                                               const int* __restrict__ cols,
                                               const float* __restrict__ adj,
                                               const float* __restrict__ S,
                                               const unsigned* __restrict__ Sb,
                                               float* __restrict__ m2_g,
                                               float* __restrict__ tr_g,
                                               float* __restrict__ left_g) {
    float m2l = 0.f, trl = 0.f;
    float lf[KC];
    #pragma unroll
    for (int k = 0; k < KC; k++) lf[k] = 0.f;

    int stride = gridDim.x * blockDim.x;
    for (int e = blockIdx.x * blockDim.x + threadIdx.x; e < NE; e += stride) {
        int r = rows[e], c = cols[e];
        float a = adj[e];
        float sv[KC], cv[KC];
        if (BF16) {
            const uint4* sr = (const uint4*)(Sb + (size_t)r * 8);
            const uint4* sc = (const uint4*)(Sb + (size_t)c * 8);
            uint4 a0 = sr[0], a1 = sr[1];
            uint4 b0 = sc[0], b1 = sc[1];
            sv[0]=bflo(a0.x); sv[1]=bfhi(a0.x); sv[2]=bflo(a0.y);  sv[3]=bfhi(a0.y);
            sv[4]=bflo(a0.z); sv[5]=bfhi(a0.z); sv[6]=bflo(a0.w);  sv[7]=bfhi(a0.w);
            sv[8]=bflo(a1.x); sv[9]=bfhi(a1.x); sv[10]=bflo(a1.y); sv[11]=bfhi(a1.y);
            sv[12]=bflo(a1.z);sv[13]=bfhi(a1.z);sv[14]=bflo(a1.w); sv[15]=bfhi(a1.w);
            cv[0]=bflo(b0.x); cv[1]=bfhi(b0.x); cv[2]=bflo(b0.y);  cv[3]=bfhi(b0.y);
            cv[4]=bflo(b0.z); cv[5]=bfhi(b0.z); cv[6]=bflo(b0.w);  cv[7]=bfhi(b0.w);
            cv[8]=bflo(b1.x); cv[9]=bfhi(b1.x); cv[10]=bflo(b1.y); cv[11]=bfhi(b1.y);
            cv[12]=bflo(b1.z);cv[13]=bfhi(b1.z);cv[14]=bflo(b1.w); cv[15]=bfhi(b1.w);
        } else {
            const float4* sr = (const float4*)(S + (size_t)r * KC);
            const float4* sc = (const float4*)(S + (size_t)c * KC);
            #pragma unroll
            for (int qq = 0; qq < 4; qq++) {
                float4 s4 = sr[qq], c4 = sc[qq];
                sv[4*qq]=s4.x; sv[4*qq+1]=s4.y; sv[4*qq+2]=s4.z; sv[4*qq+3]=s4.w;
                cv[4*qq]=c4.x; cv[4*qq+1]=c4.y; cv[4*qq+2]=c4.z; cv[4*qq+3]=c4.w;
            }
        }
        float dd = 0.f;
        #pragma unroll
        for (int k = 0; k < KC; k++) {
            dd += sv[k] * cv[k];
            lf[k] += a * sv[k];
        }
        m2l += a;
        trl += a * dd;
    }

    #pragma unroll
    for (int off = 32; off >= 1; off >>= 1) {
        m2l += __shfl_xor(m2l, off);
        trl += __shfl_xor(trl, off);
    }
    #pragma unroll
    for (int k = 0; k < KC; k++) {
        float v = lf[k];
        #pragma unroll
        for (int off = 32; off >= 1; off >>= 1) v += __shfl_xor(v, off);
        lf[k] = v;
    }
    __shared__ float red[4][18];
    int w = threadIdx.x >> 6;
    if ((threadIdx.x & 63) == 0) {
        red[w][0] = m2l; red[w][1] = trl;
        #pragma unroll
        for (int k = 0; k < KC; k++) red[w][2 + k] = lf[k];
    }
    __syncthreads();
    int t = threadIdx.x;
    if (t < 18) {
        float v = red[0][t] + red[1][t] + red[2][t] + red[3][t];
        float* dst = (t == 0) ? m2_g : (t == 1) ? tr_g : &left_g[t - 2];
        atomicAdd(dst, v);
    }
}

// ---------------------------------------------------------------------------
// epilogue: features_pooled = selu(stx/cs), spectral & collapse losses (f32)
// ---------------------------------------------------------------------------
__global__ __launch_bounds__(256) void k_final(const float* __restrict__ cs,
                                               const float* __restrict__ left,
                                               const float* __restrict__ m2p,
                                               const float* __restrict__ trp,
                                               const float* __restrict__ stx,
                                               float* __restrict__ out) {
    int t = threadIdx.x;
    #pragma unroll
    for (int k = 0; k < KC; k++) {
        float v = stx[k * DIM + t] / cs[k];
        float r = (v > 0.f) ? 1.0507009873554805f * v
                            : 1.7580993408473766f * (__expf(v) - 1.f);
        out[k * DIM + t] = r;
    }
    if (t == 0) {
        float m2 = *m2p;
        float tn = 0.f;
        #pragma unroll
        for (int k = 0; k < KC; k++) tn += left[k] * left[k];
        tn /= m2;
        float spectral = -((*trp) - tn) / m2;
        float ss = 0.f;
        #pragma unroll
        for (int k = 0; k < KC; k++) ss += cs[k] * cs[k];
        float collapse = 0.1f * (sqrtf(ss) / (float)N_NODES * 4.0f - 1.0f);
        out[KC * DIM + (size_t)N_NODES * KC]     = spectral;
        out[KC * DIM + (size_t)N_NODES * KC + 1] = collapse;
    }
}

extern "C" void kernel_launch(void* const* d_in, const int* in_sizes, int n_in,
                              void* d_out, int out_size, void* d_ws, size_t ws_size,
                              hipStream_t stream) {
    (void)out_size;

    const float* X    = nullptr;
    const int*   ei   = nullptr;
    const float* adj  = nullptr;
    const float* W    = nullptr;
    const float* bias = nullptr;
    for (int i = 0; i < n_in; i++) {
        switch (in_sizes[i]) {
            case 25600000: X    = (const float*)d_in[i]; break;
            case  6400000: ei   = (const int*)d_in[i];   break;
            case  3200000: adj  = (const float*)d_in[i]; break;
            case     4096: W    = (const float*)d_in[i]; break;
            case       16: bias = (const float*)d_in[i]; break;
        }
    }

    float* out = (float*)d_out;
    float* S   = out + KC * DIM;    // assignments [100000,16] f32
    const int* rows = ei;
    const int* cols = ei + NE;

    float* ws   = (float*)d_ws;
    float* cs   = ws;
    float* left = ws + 16;
    float* m2   = ws + 32;
    float* tr   = ws + 33;
    float* stx  = ws + 64;
    unsigned* Sb = (unsigned*)(ws + 64 + KC * DIM);
    const size_t need = (64 + KC * DIM) * sizeof(float) + (size_t)N_NODES * 32;
    const bool use_bf16 = (ws_size >= need);   // fixed per process -> graph-safe

    hipMemsetAsync(d_ws, 0, (64 + KC * DIM) * sizeof(float), stream);

    const int agrid = 1042;   // ~3 chunks/block over 3125 chunks
    if (use_bf16) {
        k_assign_stx<true><<<agrid, 256, 0, stream>>>(
            (const float4*)X, (const float4*)W, bias, S, Sb, cs, stx);
        k_edges<true><<<2048, 256, 0, stream>>>(rows, cols, adj, S, Sb, m2, tr, left);
    } else {
        k_assign_stx<false><<<agrid, 256, 0, stream>>>(
            (const float4*)X, (const float4*)W, bias, S, Sb, cs, stx);
        k_edges<false><<<2048, 256, 0, stream>>>(rows, cols, adj, S, Sb, m2, tr, left);
    }
    k_final<<<1, 256, 0, stream>>>(cs, left, m2, tr, stx, out);
}

// Round 9
// 273.581 us; speedup vs baseline: 1.1956x; 1.1956x over previous
//
#include <hip/hip_runtime.h>

#define N_NODES 100000
#define DIM 256
#define KC 16
#define NE 3200000
#define CHUNK 64
#define NCHUNKS ((N_NODES + CHUNK - 1) / CHUNK)   // 1563 (last chunk = 32 nodes)

using bf16x8 = __attribute__((ext_vector_type(8))) short;
using f32x4  = __attribute__((ext_vector_type(4))) float;

__device__ __forceinline__ float bflo(unsigned u) { return __uint_as_float(u << 16); }
__device__ __forceinline__ float bfhi(unsigned u) { return __uint_as_float(u & 0xffff0000u); }
__device__ __forceinline__ unsigned short f2bf(float f) {  // RNE
    unsigned u = __float_as_uint(f);
    return (unsigned short)((u + 0x7fffu + ((u >> 16) & 1u)) >> 16);
}
__device__ __forceinline__ unsigned packbf(float a, float b) {
    return (unsigned)f2bf(a) | ((unsigned)f2bf(b) << 16);
}

// ---------------------------------------------------------------------------
// Fused assignment + S^T X, MFMA phase A.
//  stage:   X chunk (64 rows) -> LDS bf16 (stride 264), coalesced f32 loads.
//  phase A: logits = X·W^T via mfma_f32_16x16x32_bf16 (wave w owns nodes
//           w*16..w*16+15; W held as 8 register B-frags). Softmax across the
//           C-layout col dimension (butterfly over lane bits 0-3). Writes
//           S (f32, d_out), Sb (bf16, ws), ps (LDS), cs (reg accumulator).
//  phase B: thread t owns column d=t; st[k] += ps[i][k] * Xbf[i][d].
// ---------------------------------------------------------------------------
template <bool WRITE_BF16>
__global__ __launch_bounds__(256) void k_assign_stx(const float4* __restrict__ X4,
                                                    const float4* __restrict__ W4,
                                                    const float* __restrict__ bias,
                                                    float* __restrict__ S,
                                                    unsigned* __restrict__ Sb,
                                                    float* __restrict__ cs_g,
                                                    float* __restrict__ stx) {
    __shared__ unsigned short Xbf[CHUNK * 264];   // 33.8 KB, row stride 264 bf16
    __shared__ float ps[CHUNK * 20];              // p[node][16], stride 20 (f4-aligned)
    __shared__ float csred[4][KC];

    const int lane = threadIdx.x & 63;
    const int wv   = threadIdx.x >> 6;
    const int col  = lane & 15;          // MFMA col (cluster) / A-frag row
    const int quad = lane >> 4;
    const int d    = threadIdx.x;        // phase-B column

    // ---- W -> 8 register B-frags (once per block). B = W^T, i.e. W[n][k]
    // row-major = "B^T input": lane holds W[col][s*32 + quad*8 + j], j=0..7.
    bf16x8 wfrag[8];
    #pragma unroll
    for (int s = 0; s < 8; s++) {
        float4 wa = W4[col * 64 + s * 8 + quad * 2];
        float4 wb = W4[col * 64 + s * 8 + quad * 2 + 1];
        union { bf16x8 v; unsigned u[4]; } wf;
        wf.u[0] = packbf(wa.x, wa.y);
        wf.u[1] = packbf(wa.z, wa.w);
        wf.u[2] = packbf(wb.x, wb.y);
        wf.u[3] = packbf(wb.z, wb.w);
        wfrag[s] = wf.v;
    }
    const float bk = bias[col];

    float st[KC];
    #pragma unroll
    for (int k = 0; k < KC; k++) st[k] = 0.f;
    float csacc = 0.f;

    for (int ch = blockIdx.x; ch < NCHUNKS; ch += gridDim.x) {
        const int base = ch * CHUNK;
        __syncthreads();   // Xbf/ps free (previous phase B done)

        // ---- stage X chunk as bf16 (coalesced: 64 lanes x consecutive f4)
        {
            const int c4 = threadIdx.x & 63;
            const int r0 = threadIdx.x >> 6;
            #pragma unroll 4
            for (int s = 0; s < 16; s++) {
                int r = r0 + 4 * s;
                int rg = base + r;
                if (rg >= N_NODES) rg = N_NODES - 1;
                float4 x = X4[(size_t)rg * 64 + c4];
                *((uint2*)&Xbf[r * 264 + c4 * 4]) =
                    make_uint2(packbf(x.x, x.y), packbf(x.z, x.w));
            }
        }
        __syncthreads();

        // ---- phase A: 8 MFMAs -> logits for this wave's 16 nodes
        f32x4 acc = {0.f, 0.f, 0.f, 0.f};
        #pragma unroll
        for (int s = 0; s < 8; s++) {
            bf16x8 a = *(const bf16x8*)&Xbf[(wv * 16 + col) * 264 + s * 32 + quad * 8];
            acc = __builtin_amdgcn_mfma_f32_16x16x32_bf16(a, wfrag[s], acc, 0, 0, 0);
        }
        // softmax across cols (lanes 0-15 of each quad-group), per reg
        #pragma unroll
        for (int r = 0; r < 4; r++) {
            float lg = acc[r] + bk;
            float m = lg;
            #pragma unroll
            for (int off = 8; off >= 1; off >>= 1) m = fmaxf(m, __shfl_xor(m, off));
            float e = __expf(lg - m);
            float ssum = e;
            #pragma unroll
            for (int off = 8; off >= 1; off >>= 1) ssum += __shfl_xor(ssum, off);
            float pv = e / ssum;

            int nd = base + wv * 16 + quad * 4 + r;       // C-layout row -> node
            bool val = (nd < N_NODES);
            if (!val) pv = 0.f;
            if (val) S[(size_t)nd * KC + col] = pv;       // 16 lanes -> 64 B
            ps[(wv * 16 + quad * 4 + r) * 20 + col] = pv; // conflict-free
            csacc += pv;
            float ph = __shfl_xor(pv, 1);                 // pair for bf16 pack
            if (WRITE_BF16 && val && !(col & 1))
                Sb[(size_t)nd * 8 + (col >> 1)] = packbf(pv, ph);
        }
        __syncthreads();

        // ---- phase B: st[k] += p[i][k] * X[i][d]
        #pragma unroll 4
        for (int i = 0; i < CHUNK; i++) {
            float x = bflo((unsigned)Xbf[i * 264 + d]);   // 2-way alias: free
            const float4* pp = (const float4*)&ps[i * 20];
            float4 p0 = pp[0], p1 = pp[1], p2 = pp[2], p3 = pp[3];
            st[0]  += p0.x * x; st[1]  += p0.y * x; st[2]  += p0.z * x; st[3]  += p0.w * x;
            st[4]  += p1.x * x; st[5]  += p1.y * x; st[6]  += p1.z * x; st[7]  += p1.w * x;
            st[8]  += p2.x * x; st[9]  += p2.y * x; st[10] += p2.z * x; st[11] += p2.w * x;
            st[12] += p3.x * x; st[13] += p3.y * x; st[14] += p3.z * x; st[15] += p3.w * x;
        }
    }

    // ---- epilogues
    #pragma unroll
    for (int k = 0; k < KC; k++) atomicAdd(&stx[k * DIM + d], st[k]);

    csacc += __shfl_xor(csacc, 16);
    csacc += __shfl_xor(csacc, 32);
    if (lane < KC) csred[wv][col] = csacc;
    __syncthreads();
    if (threadIdx.x < KC) {
        int t = threadIdx.x;
        atomicAdd(&cs_g[t], csred[0][t] + csred[1][t] + csred[2][t] + csred[3][t]);
    }
}

// ---------------------------------------------------------------------------
// Per-edge fused: m2 += adj; tr += adj*dot(S[row],S[col]); left += adj*S[row].
// ---------------------------------------------------------------------------
template <bool BF16>
__global__ __launch_bounds__(256) void k_edges(const int* __restrict__ rows,
                                               const int* __restrict__ cols,
                                               const float* __restrict__ adj,
                                               const float* __restrict__ S,
                                               const unsigned* __restrict__ Sb,
                                               float* __restrict__ m2_g,
                                               float* __restrict__ tr_g,
                                               float* __restrict__ left_g) {
    float m2l = 0.f, trl = 0.f;
    float lf[KC];
    #pragma unroll
    for (int k = 0; k < KC; k++) lf[k] = 0.f;

    int stride = gridDim.x * blockDim.x;
    for (int e = blockIdx.x * blockDim.x + threadIdx.x; e < NE; e += stride) {
        int r = rows[e], c = cols[e];
        float a = adj[e];
        float sv[KC], cv[KC];
        if (BF16) {
            const uint4* sr = (const uint4*)(Sb + (size_t)r * 8);
            const uint4* sc = (const uint4*)(Sb + (size_t)c * 8);
            uint4 a0 = sr[0], a1 = sr[1];
            uint4 b0 = sc[0], b1 = sc[1];
            sv[0]=bflo(a0.x); sv[1]=bfhi(a0.x); sv[2]=bflo(a0.y);  sv[3]=bfhi(a0.y);
            sv[4]=bflo(a0.z); sv[5]=bfhi(a0.z); sv[6]=bflo(a0.w);  sv[7]=bfhi(a0.w);
            sv[8]=bflo(a1.x); sv[9]=bfhi(a1.x); sv[10]=bflo(a1.y); sv[11]=bfhi(a1.y);
            sv[12]=bflo(a1.z);sv[13]=bfhi(a1.z);sv[14]=bflo(a1.w); sv[15]=bfhi(a1.w);
            cv[0]=bflo(b0.x); cv[1]=bfhi(b0.x); cv[2]=bflo(b0.y);  cv[3]=bfhi(b0.y);
            cv[4]=bflo(b0.z); cv[5]=bfhi(b0.z); cv[6]=bflo(b0.w);  cv[7]=bfhi(b0.w);
            cv[8]=bflo(b1.x); cv[9]=bfhi(b1.x); cv[10]=bflo(b1.y); cv[11]=bfhi(b1.y);
            cv[12]=bflo(b1.z);cv[13]=bfhi(b1.z);cv[14]=bflo(b1.w); cv[15]=bfhi(b1.w);
        } else {
            const float4* sr = (const float4*)(S + (size_t)r * KC);
            const float4* sc = (const float4*)(S + (size_t)c * KC);
            #pragma unroll
            for (int qq = 0; qq < 4; qq++) {
                float4 s4 = sr[qq], c4 = sc[qq];
                sv[4*qq]=s4.x; sv[4*qq+1]=s4.y; sv[4*qq+2]=s4.z; sv[4*qq+3]=s4.w;
                cv[4*qq]=c4.x; cv[4*qq+1]=c4.y; cv[4*qq+2]=c4.z; cv[4*qq+3]=c4.w;
            }
        }
        float dd = 0.f;
        #pragma unroll
        for (int k = 0; k < KC; k++) {
            dd += sv[k] * cv[k];
            lf[k] += a * sv[k];
        }
        m2l += a;
        trl += a * dd;
    }

    #pragma unroll
    for (int off = 32; off >= 1; off >>= 1) {
        m2l += __shfl_xor(m2l, off);
        trl += __shfl_xor(trl, off);
    }
    #pragma unroll
    for (int k = 0; k < KC; k++) {
        float v = lf[k];
        #pragma unroll
        for (int off = 32; off >= 1; off >>= 1) v += __shfl_xor(v, off);
        lf[k] = v;
    }
    __shared__ float red[4][18];
    int w = threadIdx.x >> 6;
    if ((threadIdx.x & 63) == 0) {
        red[w][0] = m2l; red[w][1] = trl;
        #pragma unroll
        for (int k = 0; k < KC; k++) red[w][2 + k] = lf[k];
    }
    __syncthreads();
    int t = threadIdx.x;
    if (t < 18) {
        float v = red[0][t] + red[1][t] + red[2][t] + red[3][t];
        float* dst = (t == 0) ? m2_g : (t == 1) ? tr_g : &left_g[t - 2];
        atomicAdd(dst, v);
    }
}

// ---------------------------------------------------------------------------
// epilogue: features_pooled = selu(stx/cs), spectral & collapse losses (f32)
// ---------------------------------------------------------------------------
__global__ __launch_bounds__(256) void k_final(const float* __restrict__ cs,
                                               const float* __restrict__ left,
                                               const float* __restrict__ m2p,
                                               const float* __restrict__ trp,
                                               const float* __restrict__ stx,
                                               float* __restrict__ out) {
    int t = threadIdx.x;
    #pragma unroll
    for (int k = 0; k < KC; k++) {
        float v = stx[k * DIM + t] / cs[k];
        float r = (v > 0.f) ? 1.0507009873554805f * v
                            : 1.7580993408473766f * (__expf(v) - 1.f);
        out[k * DIM + t] = r;
    }
    if (t == 0) {
        float m2 = *m2p;
        float tn = 0.f;
        #pragma unroll
        for (int k = 0; k < KC; k++) tn += left[k] * left[k];
        tn /= m2;
        float spectral = -((*trp) - tn) / m2;
        float ss = 0.f;
        #pragma unroll
        for (int k = 0; k < KC; k++) ss += cs[k] * cs[k];
        float collapse = 0.1f * (sqrtf(ss) / (float)N_NODES * 4.0f - 1.0f);
        out[KC * DIM + (size_t)N_NODES * KC]     = spectral;
        out[KC * DIM + (size_t)N_NODES * KC + 1] = collapse;
    }
}

extern "C" void kernel_launch(void* const* d_in, const int* in_sizes, int n_in,
                              void* d_out, int out_size, void* d_ws, size_t ws_size,
                              hipStream_t stream) {
    (void)out_size;

    const float* X    = nullptr;
    const int*   ei   = nullptr;
    const float* adj  = nullptr;
    const float* W    = nullptr;
    const float* bias = nullptr;
    for (int i = 0; i < n_in; i++) {
        switch (in_sizes[i]) {
            case 25600000: X    = (const float*)d_in[i]; break;
            case  6400000: ei   = (const int*)d_in[i];   break;
            case  3200000: adj  = (const float*)d_in[i]; break;
            case     4096: W    = (const float*)d_in[i]; break;
            case       16: bias = (const float*)d_in[i]; break;
        }
    }

    float* out = (float*)d_out;
    float* S   = out + KC * DIM;    // assignments [100000,16] f32
    const int* rows = ei;
    const int* cols = ei + NE;

    float* ws   = (float*)d_ws;
    float* cs   = ws;
    float* left = ws + 16;
    float* m2   = ws + 32;
    float* tr   = ws + 33;
    float* stx  = ws + 64;
    unsigned* Sb = (unsigned*)(ws + 64 + KC * DIM);
    const size_t need = (64 + KC * DIM) * sizeof(float) + (size_t)N_NODES * 32;
    const bool use_bf16 = (ws_size >= need);   // fixed per process -> graph-safe

    hipMemsetAsync(d_ws, 0, (64 + KC * DIM) * sizeof(float), stream);

    const int agrid = 782;   // 2 chunks/block over 1563 chunks, ~3 blocks/CU
    if (use_bf16) {
        k_assign_stx<true><<<agrid, 256, 0, stream>>>(
            (const float4*)X, (const float4*)W, bias, S, Sb, cs, stx);
        k_edges<true><<<2048, 256, 0, stream>>>(rows, cols, adj, S, Sb, m2, tr, left);
    } else {
        k_assign_stx<false><<<agrid, 256, 0, stream>>>(
            (const float4*)X, (const float4*)W, bias, S, Sb, cs, stx);
        k_edges<false><<<2048, 256, 0, stream>>>(rows, cols, adj, S, Sb, m2, tr, left);
    }
    k_final<<<1, 256, 0, stream>>>(cs, left, m2, tr, stx, out);
}